// Round 1
// baseline (565.516 us; speedup 1.0000x reference)
//
#include <hip/hip_runtime.h>
#include <hip/hip_bf16.h>
#include <math.h>

// GAT 2-layer, N=50000, E=800000 (+N self loops), D=64, H=2.
// Strategy:
//  - alpha depends only on dst -> per-node logits s[n,h].
//  - aggr[n] = deg(n)*h_lin[n] + sum_e softmax_w(e)*h_lin[dst_e]  (online softmax per node)
//  - CSR build (count/scan/scatter) per call; one wave per node for aggregation.

#define D 64
#define HL 128  // H*D

__global__ void zero_kernel(int* p, int n) {
    int i = blockIdx.x * blockDim.x + threadIdx.x;
    if (i < n) p[i] = 0;
}

__global__ void copy_kernel(const int* __restrict__ a, int* __restrict__ b, int n) {
    int i = blockIdx.x * blockDim.x + threadIdx.x;
    if (i < n) b[i] = a[i];
}

__global__ void count_kernel(const int* __restrict__ ei, int* __restrict__ deg, int E, int N) {
    int e = blockIdx.x * blockDim.x + threadIdx.x;
    int total = E + N;
    if (e >= total) return;
    int s = (e < E) ? ei[e] : (e - E);
    atomicAdd(&deg[s], 1);
}

__global__ void scatter_kernel(const int* __restrict__ ei, int* __restrict__ cursor,
                               int* __restrict__ colarr, int E, int N) {
    int e = blockIdx.x * blockDim.x + threadIdx.x;
    int total = E + N;
    if (e >= total) return;
    int s, d;
    if (e < E) { s = ei[e]; d = ei[E + e]; }
    else       { s = e - E; d = e - E; }
    int pos = atomicAdd(&cursor[s], 1);
    colarr[pos] = d;
}

// single-block exclusive scan over n ints (n ~ 50k, runs once per call, cheap)
__global__ __launch_bounds__(1024) void scan_kernel(const int* __restrict__ deg,
                                                    int* __restrict__ row_ptr, int n) {
    __shared__ int buf[1024];
    int tid = threadIdx.x;
    int carry = 0;
    for (int base = 0; base < n; base += 1024) {
        int i = base + tid;
        int v = (i < n) ? deg[i] : 0;
        __syncthreads();              // protect buf[1023] read of previous iter
        buf[tid] = v;
        __syncthreads();
        for (int off = 1; off < 1024; off <<= 1) {
            int t = (tid >= off) ? buf[tid - off] : 0;
            __syncthreads();
            buf[tid] += t;
            __syncthreads();
        }
        if (i < n) row_ptr[i] = carry + buf[tid] - v;   // exclusive
        carry += buf[1023];
    }
    if (tid == 0) row_ptr[n] = carry;
}

__global__ void embed_kernel(const int* __restrict__ x, const float* __restrict__ emb,
                             float* __restrict__ h, int n) {
    int i = blockIdx.x * blockDim.x + threadIdx.x;
    if (i >= n * D) return;
    int node = i >> 6, d = i & 63;
    h[i] = emb[x[node] * D + d];
}

// h_lin = h @ W + b  (h:[n,64], W:[64,128]); fused per-node logits
// s[n,h] = leaky_relu(dot(h_lin[n,h*64:...], att[h]), 0.2)
#define TILE_NODES 32
__global__ __launch_bounds__(256) void linear_kernel(
    const float* __restrict__ h, const float* __restrict__ W,
    const float* __restrict__ b, const float* __restrict__ att,
    float* __restrict__ h_lin, float* __restrict__ s_out, int n)
{
    __shared__ float sW[64 * HL];            // 32 KB
    __shared__ float sh[TILE_NODES * D];     // 8 KB
    int t = threadIdx.x;
    for (int i = t; i < 64 * HL; i += 256) sW[i] = W[i];
    int base = blockIdx.x * TILE_NODES;
    for (int i = t; i < TILE_NODES * D; i += 256) {
        int node = base + (i >> 6);
        sh[i] = (node < n) ? h[node * D + (i & 63)] : 0.f;
    }
    __syncthreads();
    int c  = t & 127;    // output column (head = c>>6, d = c&63)
    int r0 = t >> 7;     // 0 or 1 (uniform per wave)
    float bc   = b[c];
    float attv = att[c]; // atts[l] flat [H][D] matches column layout
    for (int r = r0; r < TILE_NODES; r += 2) {
        int node = base + r;
        if (node >= n) break;                 // wave-uniform
        const float* hr = &sh[r * D];
        float acc = bc;
        #pragma unroll
        for (int k = 0; k < D; ++k) acc = fmaf(hr[k], sW[k * HL + c], acc);
        h_lin[(size_t)node * HL + c] = acc;
        // wave reduce: 64 lanes of this wave share (node, head)
        float p = acc * attv;
        #pragma unroll
        for (int off = 32; off > 0; off >>= 1) p += __shfl_down(p, off, 64);
        if ((t & 63) == 0) {
            float sv = p > 0.f ? p : 0.2f * p;   // leaky_relu
            s_out[node * 2 + (c >> 6)] = sv;
        }
    }
}

// one wave per node: online softmax over incident edges + weighted gather-sum
__global__ __launch_bounds__(256) void aggr_kernel(
    const float* __restrict__ h_lin, const float* __restrict__ s,
    const int* __restrict__ row_ptr, const int* __restrict__ col,
    const float* __restrict__ bias, float* __restrict__ out,
    int n, int do_relu)
{
    int wave = (blockIdx.x * blockDim.x + threadIdx.x) >> 6;
    int lane = threadIdx.x & 63;
    if (wave >= n) return;
    int node = wave;
    int e0 = row_ptr[node], e1 = row_ptr[node + 1];

    float m0 = -INFINITY, m1 = -INFINITY;
    float l0 = 0.f, l1 = 0.f;
    float acc0 = 0.f, acc1 = 0.f;

    for (int e = e0; e < e1; ++e) {
        int d = col[e];
        float2 sv = ((const float2*)s)[d];         // broadcast (all lanes same addr)
        const float* hv = &h_lin[(size_t)d * HL];
        float v0 = hv[lane];
        float v1 = hv[64 + lane];
        // head 0
        float nm0 = fmaxf(m0, sv.x);
        float f0  = __expf(sv.x - nm0);
        float sc0 = __expf(m0 - nm0);              // exp(-inf)=0 on first iter
        l0   = l0 * sc0 + f0;
        acc0 = acc0 * sc0 + f0 * v0;
        m0 = nm0;
        // head 1
        float nm1 = fmaxf(m1, sv.y);
        float f1  = __expf(sv.y - nm1);
        float sc1 = __expf(m1 - nm1);
        l1   = l1 * sc1 + f1;
        acc1 = acc1 * sc1 + f1 * v1;
        m1 = nm1;
    }
    float deg = (float)(e1 - e0);
    const float* hn = &h_lin[(size_t)node * HL];
    float r0v = deg * hn[lane]      + acc0 / (l0 + 1e-16f);
    float r1v = deg * hn[64 + lane] + acc1 / (l1 + 1e-16f);
    float res = 0.5f * (r0v + r1v) + bias[lane];
    if (do_relu) res = fmaxf(res, 0.f);
    out[(size_t)node * D + lane] = res;
}

extern "C" void kernel_launch(void* const* d_in, const int* in_sizes, int n_in,
                              void* d_out, int out_size, void* d_ws, size_t ws_size,
                              hipStream_t stream) {
    const int*   x      = (const int*)d_in[0];
    const int*   ei     = (const int*)d_in[1];
    const float* emb    = (const float*)d_in[2];
    const float* Ws     = (const float*)d_in[3];
    const float* bs     = (const float*)d_in[4];
    const float* atts   = (const float*)d_in[5];
    const float* biases = (const float*)d_in[6];
    float* out = (float*)d_out;

    int N  = in_sizes[0];
    int E  = in_sizes[1] / 2;
    int ET = E + N;

    char* w = (char*)d_ws;
    size_t off = 0;
    float* hA   = (float*)(w + off); off += (size_t)N * D * 4;
    float* hlin = (float*)(w + off); off += (size_t)N * HL * 4;
    float* slog = (float*)(w + off); off += (size_t)N * 2 * 4;
    int* row_ptr = (int*)(w + off);  off += (size_t)(N + 1) * 4;
    off = (off + 255) & ~(size_t)255;
    int* cursor  = (int*)(w + off);  off += (size_t)N * 4;
    off = (off + 255) & ~(size_t)255;
    int* colarr  = (int*)(w + off);  off += (size_t)ET * 4;

    // CSR build (keyed by src)
    zero_kernel<<<(N + 255) / 256, 256, 0, stream>>>(cursor, N);
    count_kernel<<<(ET + 255) / 256, 256, 0, stream>>>(ei, cursor, E, N);
    scan_kernel<<<1, 1024, 0, stream>>>(cursor, row_ptr, N);
    copy_kernel<<<(N + 255) / 256, 256, 0, stream>>>(row_ptr, cursor, N);
    scatter_kernel<<<(ET + 255) / 256, 256, 0, stream>>>(ei, cursor, colarr, E, N);

    // input embedding
    embed_kernel<<<(N * D + 255) / 256, 256, 0, stream>>>(x, emb, hA, N);

    for (int l = 0; l < 2; ++l) {
        linear_kernel<<<(N + TILE_NODES - 1) / TILE_NODES, 256, 0, stream>>>(
            hA, Ws + (size_t)l * 64 * HL, bs + (size_t)l * HL,
            atts + (size_t)l * HL, hlin, slog, N);
        float* dst = (l == 0) ? hA : out;
        aggr_kernel<<<(N + 3) / 4, 256, 0, stream>>>(
            hlin, slog, row_ptr, colarr, biases + (size_t)l * D, dst, N, l == 0 ? 1 : 0);
    }
}